// Round 5
// baseline (40.505 us; speedup 1.0000x reference)
//
#include <hip/hip_runtime.h>
#include <hip/hip_bf16.h>

// GetInitialSymbol: structured single-head cross-attention + residual, MFMA.
//   q_i = 2*tgt[136+i]-1 (i<32); k_i = 2*mem[72+i]-1; v_{200+j} = mem[8+j]; v_265 = 1
//   fixed token: score=31, value=0.
// 512-thread blocks: 8 waves = rg{0,1} x ks{0..3}; 32 t-rows, 4x512-key segments.
// All hot-loop LDS reads are linear (frag_base + lane*16B) -> conflict-free.
#define B_   8
#define T_   2048
#define S_   2048
#define DIN  512
#define QOFF 136
#define KOFF 72
#define VSRC 8

typedef __attribute__((ext_vector_type(8))) short bf16x8;
typedef __attribute__((ext_vector_type(4))) float f32x4;

constexpr int BLK  = 512;
constexpr int GK   = 32;         // keys per staged group
constexpr int SEG  = S_ / 4;     // 512 keys per ks segment
constexpr int NG   = SEG / GK;   // 16 groups
// per (ks,dbuf) buffer, ushort offsets: khi[mt*512+l*8], klo @+1024, vfrag[hh] @+2048
constexpr int BUFU = 3072;       // 6 KB

__device__ __forceinline__ ushort f2b(float x) {
  __hip_bfloat16 h = __float2bfloat16(x);
  return __builtin_bit_cast(ushort, h);
}
__device__ __forceinline__ float b2f(ushort s) {
  return __bfloat162float(__builtin_bit_cast(__hip_bfloat16, s));
}

struct Stage { float4 k4[2]; float v[8]; };

// Cohort = 2 waves (rg 0,1 of one ks), ct in [0,128). GK=32 keys per group.
__device__ __forceinline__ void stage_issue(const float* __restrict__ mb, int key0,
                                            int ct, Stage& st) {
  #pragma unroll
  for (int rep = 0; rep < 2; ++rep) {
    const int cid = ct + 128 * rep;
    const int key = cid >> 3, c = cid & 7;          // coalesced 16B per lane
    st.k4[rep] = *(const float4*)(mb + (size_t)(key0 + key) * DIN + KOFF + 4 * c);
  }
  const int ch = ct & 31, h = ct >> 5;              // lane: 1 channel x 8 keys
  #pragma unroll
  for (int r = 0; r < 8; ++r)
    st.v[r] = mb[(size_t)(key0 + 8 * h + r) * DIN + VSRC + ch];
}

__device__ __forceinline__ void stage_write(ushort* __restrict__ buf, int ct,
                                            const Stage& st) {
  // K fragments in wave-linear order: value K'[key][e] -> tile mt=key>>4,
  // lane l=(key&15)+16*(e>>3), slot j=e&7; pos = mt*512 + l*8 + j.
  #pragma unroll
  for (int rep = 0; rep < 2; ++rep) {
    const int cid = ct + 128 * rep;
    const int key = cid >> 3, c = cid & 7;
    const float* kf = (const float*)&st.k4[rep];
    ushort h4[4], l4[4];
    #pragma unroll
    for (int e = 0; e < 4; ++e) {
      const float p  = 2.f * kf[e] - 1.f;           // k' = 2*mem - 1 (hi/lo split)
      const ushort hb = f2b(p);
      h4[e] = hb;
      l4[e] = f2b(p - b2f(hb));
    }
    const int pos = (key >> 4) * 512 + ((key & 15) + 16 * (c >> 1)) * 8 + 4 * (c & 1);
    *(uint2*)(buf + pos)        = *(const uint2*)h4;
    *(uint2*)(buf + 1024 + pos) = *(const uint2*)l4;
  }
  // V fragments: slot (Q=l>>4, j) <-> key kappa = (j>>2)*16 + 4*Q + (j&3); value
  // V[key][ch] -> pos = 2048 + (ch>>4)*512 + (((key>>2)&3)*16 + (ch&15))*8
  //                + (key>>4)*4 + (key&3).
  const int ch = ct & 31, h = ct >> 5;
  const int hh = ch >> 4, c15 = ch & 15;
  ushort v4[8];
  #pragma unroll
  for (int r = 0; r < 8; ++r) v4[r] = f2b(st.v[r]);
  #pragma unroll
  for (int half = 0; half < 2; ++half) {            // keys 8h+4*half+(0..3)
    const int Q   = (2 * h + half) & 3;
    const int pos = 2048 + hh * 512 + (Q * 16 + c15) * 8 + (h >> 1) * 4;
    *(uint2*)(buf + pos) = *(const uint2*)&v4[half * 4];
  }
}

__device__ __forceinline__ void merge_write(float* d, int lane, float m, float ls,
                                            const f32x4& o0, const f32x4& o1) {
  d[lane] = m;
  d[64 + lane] = ls;
  #pragma unroll
  for (int i = 0; i < 4; ++i) {
    d[128 + i * 64 + lane] = o0[i];
    d[384 + i * 64 + lane] = o1[i];
  }
}

__device__ __forceinline__ void merge_read(const float* s, int lane, float& m,
                                           float& ls, f32x4& o0, f32x4& o1) {
  const float m1 = s[lane], l1 = s[64 + lane];
  const float mn = fmaxf(m, m1);
  const float sa = __expf(m - mn), sb = __expf(m1 - mn);
  ls = ls * sa + l1 * sb;
  #pragma unroll
  for (int i = 0; i < 4; ++i) {
    o0[i] = o0[i] * sa + s[128 + i * 64 + lane] * sb;
    o1[i] = o1[i] * sa + s[384 + i * 64 + lane] * sb;
  }
  m = mn;
}

__global__ __launch_bounds__(BLK)
void attn_mfma(const float* __restrict__ tgt, const float* __restrict__ mem,
               float* __restrict__ out) {
  __shared__ ushort stage[4][2][BUFU];   // 48 KB; merge slots overlay afterwards
  __shared__ float  olds[2][560];        // per-rg results: [33 ch][17] layout

  const int tid  = threadIdx.x;
  const int lane = tid & 63;
  const int wv   = tid >> 6;
  const int ks   = wv >> 1;              // key segment 0..3
  const int rg   = wv & 1;               // 16-row tile 0..1
  const int Q    = lane >> 4;
  const int r15  = lane & 15;
  const int ct   = rg * 64 + lane;       // id within 2-wave staging cohort

  // XCD swizzle: batch == XCD (each XCD's L2 keeps one batch's K/V slices hot).
  const int o  = (blockIdx.x & 7) * 64 + (blockIdx.x >> 3);
  const int b  = o >> 6;
  const int t0 = (o & 63) * 32;

  const float* mb   = mem + (size_t)b * S_ * DIN;
  const int    key0 = ks * SEG;

  Stage st;
  stage_issue(mb, key0, ct, st);

  // P fragments: element j of lane = p[qrow=r15][8Q+j], hi/lo bf16 split.
  const float* trow = tgt + (size_t)(b * T_ + t0 + rg * 16 + r15) * DIN + QOFF + 8 * Q;
  float4 qa = *(const float4*)trow;
  float4 qb = *(const float4*)(trow + 4);
  bf16x8 phi, plo;
  {
    const float pv[8] = {qa.x, qa.y, qa.z, qa.w, qb.x, qb.y, qb.z, qb.w};
    #pragma unroll
    for (int e = 0; e < 8; ++e) {
      const float p  = 2.f * pv[e] - 1.f;
      const ushort hb = f2b(p);
      phi[e] = (short)hb;
      plo[e] = (short)f2b(p - b2f(hb));
    }
  }

  float m  = 31.f;                               // fixed token score (exact)
  float ls = (Q == 0 && ks == 0) ? 1.f : 0.f;    // its exp, seeded once per row
  f32x4 oc0 = {0.f, 0.f, 0.f, 0.f}, oc1 = {0.f, 0.f, 0.f, 0.f};

  stage_write(&stage[ks][0][0], ct, st);
  __syncthreads();

  for (int g = 0; g < NG; ++g) {
    if (g + 1 < NG) stage_issue(mb, key0 + (g + 1) * GK, ct, st);  // issue early
    const ushort* buf = &stage[ks][g & 1][0];

    // ---- scores: 2 tiles x 16 keys; C elem r of lane = score[4Q+r][r15]
    f32x4 c4[2];
    #pragma unroll
    for (int mt = 0; mt < 2; ++mt) {
      const bf16x8 khi = *(const bf16x8*)(buf + mt * 512 + lane * 8);         // linear
      const bf16x8 klo = *(const bf16x8*)(buf + 1024 + mt * 512 + lane * 8);  // linear
      f32x4 z = {0.f, 0.f, 0.f, 0.f};
      z = __builtin_amdgcn_mfma_f32_16x16x32_bf16(khi, phi, z, 0, 0, 0);
      z = __builtin_amdgcn_mfma_f32_16x16x32_bf16(khi, plo, z, 0, 0, 0);
      z = __builtin_amdgcn_mfma_f32_16x16x32_bf16(klo, phi, z, 0, 0, 0);
      c4[mt] = z;
    }

    // ---- online softmax (deferred rescale: scores rarely exceed 31)
    float gm = c4[0][0];
    #pragma unroll
    for (int mt = 0; mt < 2; ++mt)
      #pragma unroll
      for (int r = 0; r < 4; ++r) gm = fmaxf(gm, c4[mt][r]);
    gm = fmaxf(gm, __shfl_xor(gm, 16));
    gm = fmaxf(gm, __shfl_xor(gm, 32));
    if (__any(gm > m)) {
      const float mn  = fmaxf(m, gm);
      const float scl = __expf(m - mn);
      m = mn;
      ls *= scl;
      #pragma unroll
      for (int i = 0; i < 4; ++i) { oc0[i] *= scl; oc1[i] *= scl; }
    }

    // W frag: slot j <-> key (j>>2)*16 + 4Q + (j&3) == c4[j>>2][j&3] (same lane)
    bf16x8 wf;
    float wsum = 0.f;
    #pragma unroll
    for (int j = 0; j < 8; ++j) {
      const float w = __expf(c4[j >> 2][j & 3] - m);
      wsum += w;
      wf[j] = (short)f2b(w);
    }
    ls += wsum;

    // ---- PV: oc[hh] += Vfrag(hh) x W  (A,B share the slot->key bijection)
    const bf16x8 vf0 = *(const bf16x8*)(buf + 2048 + lane * 8);        // linear
    const bf16x8 vf1 = *(const bf16x8*)(buf + 2048 + 512 + lane * 8);  // linear
    oc0 = __builtin_amdgcn_mfma_f32_16x16x32_bf16(vf0, wf, oc0, 0, 0, 0);
    oc1 = __builtin_amdgcn_mfma_f32_16x16x32_bf16(vf1, wf, oc1, 0, 0, 0);

    __syncthreads();
    if (g + 1 < NG) stage_write(&stage[ks][(g + 1) & 1][0], ct, st);
    __syncthreads();
  }

  // ---- merge 4 ks segments -> ks0 (2 rounds), overlay on staging LDS
  float* msl = (float*)&stage[0][0][0];   // slots: (slot*2 + rg)*640 floats
  if (ks >= 2) merge_write(msl + ((ks - 2) * 2 + rg) * 640, lane, m, ls, oc0, oc1);
  __syncthreads();
  if (ks < 2) merge_read(msl + (ks * 2 + rg) * 640, lane, m, ls, oc0, oc1);
  __syncthreads();
  if (ks == 1) merge_write(msl + rg * 640, lane, m, ls, oc0, oc1);
  __syncthreads();
  if (ks == 0) {
    merge_read(msl + rg * 640, lane, m, ls, oc0, oc1);
    float t2 = ls + __shfl_xor(ls, 16);          // sum partials across Q-groups
    const float lt  = t2 + __shfl_xor(t2, 32);
    const float inv = 1.f / lt;
    #pragma unroll
    for (int i = 0; i < 4; ++i) {
      olds[rg][(4 * Q + i) * 17 + r15]      = oc0[i] * inv;   // ch 0..15
      olds[rg][(16 + 4 * Q + i) * 17 + r15] = oc1[i] * inv;   // ch 16..31
    }
    if (Q == 0) olds[rg][32 * 17 + r15] = 1.f - __expf(31.f - m) * inv;
  }
  __syncthreads();

  // ---- epilogue: out = tgt + sparse update (ch 200..231 and 265); 32 rows
  const size_t base = (size_t)(b * T_ + t0) * DIN;
  #pragma unroll
  for (int k = 0; k < 8; ++k) {
    const int vid = tid + BLK * k;          // 32 rows x 128 float4
    const int row = vid >> 7;
    const int c4i = vid & 127;
    const size_t off = base + (size_t)row * DIN + c4i * 4;
    float4 ov = *(const float4*)(tgt + off);
    const int rg2 = row >> 4, rr = row & 15;
    if (c4i >= 50 && c4i < 58) {            // channels 200..231
      const int j = (c4i - 50) * 4;
      ov.x += olds[rg2][(j + 0) * 17 + rr];
      ov.y += olds[rg2][(j + 1) * 17 + rr];
      ov.z += olds[rg2][(j + 2) * 17 + rr];
      ov.w += olds[rg2][(j + 3) * 17 + rr];
    } else if (c4i == 66) {                 // channel 265 is .y of float4 66
      ov.y += olds[rg2][32 * 17 + rr];
    }
    *(float4*)(out + off) = ov;
  }
}

extern "C" void kernel_launch(void* const* d_in, const int* in_sizes, int n_in,
                              void* d_out, int out_size, void* d_ws, size_t ws_size,
                              hipStream_t stream) {
  const float* tgt = (const float*)d_in[0];
  const float* mem = (const float*)d_in[1];
  float* out = (float*)d_out;
  attn_mfma<<<dim3(B_ * (T_ / 32)), dim3(BLK), 0, stream>>>(tgt, mem, out);
}

// Round 6
// 36.927 us; speedup vs baseline: 1.0969x; 1.0969x over previous
//
#include <hip/hip_runtime.h>
#include <hip/hip_bf16.h>

// GetInitialSymbol: structured single-head cross-attention + residual.
//   q_i = 2*tgt[136+i]-1 (i<32); k_i = 2*mem[72+i]-1; v_{200+j} = mem[8+j]; v_265 = 1
//   fixed token: score=31, value=0.
// Two kernels: (1) preproc converts K (hi/lo bf16) + V (bf16) into d_ws in exact
// MFMA-fragment order, once per batch. (2) attn_main: barrier-free flash attention;
// wave = 32 qrows x 512-key segment; wave-private LDS dbuf staged via
// global_load_lds with counted vmcnt; merge across 4 waves at the end.
#define B_   8
#define T_   2048
#define S_   2048
#define DIN  512
#define QOFF 136
#define KOFF 72
#define VSRC 8

typedef __attribute__((ext_vector_type(8))) short bf16x8;
typedef __attribute__((ext_vector_type(4))) float f32x4;

constexpr int KHI = 0;               // ushort offsets in ws
constexpr int KLO = 524288;          // 8 batches x 65536
constexpr int VF  = 1048576;
constexpr int BATCH_U = 65536;       // ushorts per batch per section

constexpr int BLK = 256;             // 4 waves = 4 key segments of 512
constexpr int NGW = 16;              // 32-key groups per segment

__device__ __forceinline__ ushort f2b(float x) {
  __hip_bfloat16 h = __float2bfloat16(x);
  return __builtin_bit_cast(ushort, h);
}
__device__ __forceinline__ float b2f(ushort s) {
  return __bfloat162float(__builtin_bit_cast(__hip_bfloat16, s));
}

// ---------- kernel 1: K/V -> fragment-ordered bf16 in ws (once per batch) ----------
// K'[key][e] -> tile=key>>4, lane=(key&15)+16*(e>>3), slot=e&7: idx tile*512+lane*8+slot
// V[key][ch] -> group=key>>5, hh=ch>>4, lane=(ch&15)+16*((key>>2)&3),
//               slot=((key>>4)&1)*4+(key&3): idx group*1024+hh*512+lane*8+slot
__global__ __launch_bounds__(256)
void preproc(const float* __restrict__ mem, ushort* __restrict__ ws) {
  const int t   = threadIdx.x;
  const int b   = blockIdx.x >> 5;
  const int key = (blockIdx.x & 31) * 64 + (t >> 2);
  const int cs  = (t & 3) * 8;
  const float* row = mem + ((size_t)b * S_ + key) * DIN;
  const float4 ka = *(const float4*)(row + KOFF + cs);
  const float4 kb = *(const float4*)(row + KOFF + cs + 4);
  const float4 va = *(const float4*)(row + VSRC + cs);
  const float4 vb = *(const float4*)(row + VSRC + cs + 4);
  const float kf[8] = {ka.x, ka.y, ka.z, ka.w, kb.x, kb.y, kb.z, kb.w};
  const float vv[8] = {va.x, va.y, va.z, va.w, vb.x, vb.y, vb.z, vb.w};
  ushort khi[8], klo[8];
  #pragma unroll
  for (int e = 0; e < 8; ++e) {
    const float p  = 2.f * kf[e] - 1.f;
    const ushort hb = f2b(p);
    khi[e] = hb;
    klo[e] = f2b(p - b2f(hb));
  }
  const size_t kidx = (size_t)b * BATCH_U + (key >> 4) * 512
                    + ((key & 15) + 16 * (t & 3)) * 8;          // 8 contiguous slots
  *(uint4*)(ws + KHI + kidx) = *(const uint4*)khi;
  *(uint4*)(ws + KLO + kidx) = *(const uint4*)klo;
  const int Qk = (key >> 2) & 3;
  const int jk = ((key >> 4) & 1) * 4 + (key & 3);
  ushort* vdst = ws + VF + (size_t)b * BATCH_U + (key >> 5) * 1024 + jk;
  #pragma unroll
  for (int c = 0; c < 8; ++c) {
    const int ch = cs + c;
    vdst[(ch >> 4) * 512 + ((ch & 15) + 16 * Qk) * 8] = f2b(vv[c]);
  }
}

// ---------- merge helpers (outside hot loop) ----------
__device__ __forceinline__ void mwrite(float* d, int lane, const float* m,
                                       const float* ls, const f32x4 oc[2][2]) {
  #pragma unroll
  for (int rt = 0; rt < 2; ++rt) {
    float* dr = d + rt * 640;
    dr[lane] = m[rt];
    dr[64 + lane] = ls[rt];
    #pragma unroll
    for (int i = 0; i < 4; ++i) {
      dr[128 + i * 64 + lane] = oc[rt][0][i];
      dr[384 + i * 64 + lane] = oc[rt][1][i];
    }
  }
}
__device__ __forceinline__ void mread(const float* s, int lane, float* m,
                                      float* ls, f32x4 oc[2][2]) {
  #pragma unroll
  for (int rt = 0; rt < 2; ++rt) {
    const float* sr = s + rt * 640;
    const float m1 = sr[lane], l1 = sr[64 + lane];
    const float mn = fmaxf(m[rt], m1);
    const float sa = __expf(m[rt] - mn), sb = __expf(m1 - mn);
    ls[rt] = ls[rt] * sa + l1 * sb;
    #pragma unroll
    for (int i = 0; i < 4; ++i) {
      oc[rt][0][i] = oc[rt][0][i] * sa + sr[128 + i * 64 + lane] * sb;
      oc[rt][1][i] = oc[rt][1][i] * sa + sr[384 + i * 64 + lane] * sb;
    }
    m[rt] = mn;
  }
}

// ---------- kernel 2: flash attention, barrier-free hot loop ----------
__global__ __launch_bounds__(BLK, 3)
void attn_main(const float* __restrict__ tgt, const ushort* __restrict__ ws,
               float* __restrict__ out) {
  __shared__ __align__(16) ushort sh[4][2][3072];   // 48 KB: [wave][dbuf][6KB]

  const int tid  = threadIdx.x;
  const int lane = tid & 63;
  const int wv   = tid >> 6;              // = key segment 0..3
  const int Q    = lane >> 4;
  const int r15  = lane & 15;

  // XCD swizzle: batch == XCD (K/V fragments stay hot in that XCD's L2)
  const int o  = (blockIdx.x & 7) * 64 + (blockIdx.x >> 3);
  const int b  = o >> 6;
  const int t0 = (o & 63) * 32;

  const ushort* wkhi = ws + KHI + (size_t)b * BATCH_U;
  const ushort* wklo = ws + KLO + (size_t)b * BATCH_U;
  const ushort* wvf  = ws + VF  + (size_t)b * BATCH_U;
  const int tile0 = wv * 32;              // 512 keys -> 32 tiles of 16
  ushort* mybuf = &sh[wv][0][0];

  // ---- P fragments (2 row-tiles), hi/lo split; fully consumed before staging
  bf16x8 phi[2], plo[2];
  #pragma unroll
  for (int rt = 0; rt < 2; ++rt) {
    const float* tr = tgt + ((size_t)(b * T_) + t0 + rt * 16 + r15) * DIN + QOFF + 8 * Q;
    const float4 qa = *(const float4*)tr;
    const float4 qb = *(const float4*)(tr + 4);
    const float pv[8] = {qa.x, qa.y, qa.z, qa.w, qb.x, qb.y, qb.z, qb.w};
    #pragma unroll
    for (int e = 0; e < 8; ++e) {
      const float p  = 2.f * pv[e] - 1.f;
      const ushort hb = f2b(p);
      phi[rt][e] = (short)hb;
      plo[rt][e] = (short)f2b(p - b2f(hb));
    }
  }

  float m[2]  = {31.f, 31.f};             // fixed token score (exact)
  float ls[2];
  ls[0] = ls[1] = (Q == 0 && wv == 0) ? 1.f : 0.f;   // its exp, seeded once/qrow
  f32x4 oc[2][2] = {};                    // [rt][hh] out accumulators

  auto stage = [&](int g) {
    ushort* dst = mybuf + (g & 1) * 3072;
    #pragma unroll
    for (int mt = 0; mt < 2; ++mt) {
      const int tile = tile0 + 2 * g + mt;
      __builtin_amdgcn_global_load_lds(
          (const __attribute__((address_space(1))) void*)(wkhi + tile * 512 + lane * 8),
          (__attribute__((address_space(3))) void*)(dst + mt * 512), 16, 0, 0);
      __builtin_amdgcn_global_load_lds(
          (const __attribute__((address_space(1))) void*)(wklo + tile * 512 + lane * 8),
          (__attribute__((address_space(3))) void*)(dst + 1024 + mt * 512), 16, 0, 0);
    }
    const int gv = wv * NGW + g;
    #pragma unroll
    for (int hh = 0; hh < 2; ++hh)
      __builtin_amdgcn_global_load_lds(
          (const __attribute__((address_space(1))) void*)(wvf + gv * 1024 + hh * 512 + lane * 8),
          (__attribute__((address_space(3))) void*)(dst + 2048 + hh * 512), 16, 0, 0);
  };

  stage(0);
  stage(1);                               // 12 loads in flight

  for (int g = 0; g < NGW; ++g) {
    if (g + 1 < NGW) asm volatile("s_waitcnt vmcnt(6)" ::: "memory");   // g landed
    else             asm volatile("s_waitcnt vmcnt(0)" ::: "memory");
    __builtin_amdgcn_sched_barrier(0);
    const ushort* buf = mybuf + (g & 1) * 3072;
    const bf16x8 kh0 = *(const bf16x8*)(buf + lane * 8);                // all linear
    const bf16x8 kh1 = *(const bf16x8*)(buf + 512 + lane * 8);
    const bf16x8 kl0 = *(const bf16x8*)(buf + 1024 + lane * 8);
    const bf16x8 kl1 = *(const bf16x8*)(buf + 1536 + lane * 8);
    const bf16x8 vf0 = *(const bf16x8*)(buf + 2048 + lane * 8);
    const bf16x8 vf1 = *(const bf16x8*)(buf + 2560 + lane * 8);
    asm volatile("s_waitcnt lgkmcnt(0)" ::: "memory");   // reads done -> buf reusable
    __builtin_amdgcn_sched_barrier(0);
    if (g + 2 < NGW) stage(g + 2);        // overwrite buf[g&1] safely

    #pragma unroll
    for (int rt = 0; rt < 2; ++rt) {
      // scores: C elem r = score[key = gbase + 16*mt + 4Q + r][qrow = r15]
      f32x4 c0 = {0.f, 0.f, 0.f, 0.f}, c1 = {0.f, 0.f, 0.f, 0.f};
      c0 = __builtin_amdgcn_mfma_f32_16x16x32_bf16(kh0, phi[rt], c0, 0, 0, 0);
      c0 = __builtin_amdgcn_mfma_f32_16x16x32_bf16(kh0, plo[rt], c0, 0, 0, 0);
      c0 = __builtin_amdgcn_mfma_f32_16x16x32_bf16(kl0, phi[rt], c0, 0, 0, 0);
      c1 = __builtin_amdgcn_mfma_f32_16x16x32_bf16(kh1, phi[rt], c1, 0, 0, 0);
      c1 = __builtin_amdgcn_mfma_f32_16x16x32_bf16(kh1, plo[rt], c1, 0, 0, 0);
      c1 = __builtin_amdgcn_mfma_f32_16x16x32_bf16(kl1, phi[rt], c1, 0, 0, 0);

      // online softmax; deferred rescale
      float gm = fmaxf(fmaxf(fmaxf(c0[0], c0[1]), fmaxf(c0[2], c0[3])),
                       fmaxf(fmaxf(c1[0], c1[1]), fmaxf(c1[2], c1[3])));
      gm = fmaxf(gm, __shfl_xor(gm, 16));
      gm = fmaxf(gm, __shfl_xor(gm, 32));
      if (__any(gm > m[rt])) {
        const float mn  = fmaxf(m[rt], gm);
        const float scl = __expf(m[rt] - mn);
        m[rt] = mn;
        ls[rt] *= scl;
        #pragma unroll
        for (int i = 0; i < 4; ++i) { oc[rt][0][i] *= scl; oc[rt][1][i] *= scl; }
      }

      // W frag: slot j <-> key (j>>2)*16 + 4Q + (j&3); same bijection as V frag
      bf16x8 wf;
      float wsum = 0.f;
      #pragma unroll
      for (int j = 0; j < 8; ++j) {
        const float w = __expf(((j < 4) ? c0[j & 3] : c1[j & 3]) - m[rt]);
        wsum += w;
        wf[j] = (short)f2b(w);
      }
      ls[rt] += wsum;

      oc[rt][0] = __builtin_amdgcn_mfma_f32_16x16x32_bf16(vf0, wf, oc[rt][0], 0, 0, 0);
      oc[rt][1] = __builtin_amdgcn_mfma_f32_16x16x32_bf16(vf1, wf, oc[rt][1], 0, 0, 0);
    }
  }

  // ---- merge 4 segments -> wave 0 (overlay staging LDS; slots of 1280 floats)
  __syncthreads();
  float* msl  = (float*)&sh[0][0][0];
  float* olds = msl + 3 * 1280;           // 2 x 561 floats of results
  if (wv >= 2) mwrite(msl + (wv - 2) * 1280, lane, m, ls, oc);
  __syncthreads();
  if (wv < 2) mread(msl + wv * 1280, lane, m, ls, oc);
  __syncthreads();
  if (wv == 1) mwrite(msl, lane, m, ls, oc);
  __syncthreads();
  if (wv == 0) {
    mread(msl, lane, m, ls, oc);
    #pragma unroll
    for (int rt = 0; rt < 2; ++rt) {
      float t2 = ls[rt] + __shfl_xor(ls[rt], 16);     // sum across Q-groups
      const float lt  = t2 + __shfl_xor(t2, 32);
      const float inv = 1.f / lt;
      #pragma unroll
      for (int hh = 0; hh < 2; ++hh)
        #pragma unroll
        for (int i = 0; i < 4; ++i)
          olds[rt * 561 + (4 * Q + i + 16 * hh) * 17 + r15] = oc[rt][hh][i] * inv;
      if (Q == 0) olds[rt * 561 + 32 * 17 + r15] = 1.f - __expf(31.f - m[rt]) * inv;
    }
  }
  __syncthreads();

  // ---- epilogue: out = tgt + sparse update (ch 200..231, 265); 32 rows
  const size_t base = (size_t)(b * T_ + t0) * DIN;
  #pragma unroll
  for (int k = 0; k < 16; ++k) {
    const int vid = tid + BLK * k;        // 32 rows x 128 float4
    const int row = vid >> 7;
    const int c4i = vid & 127;
    const size_t off = base + (size_t)row * DIN + c4i * 4;
    float4 ov = *(const float4*)(tgt + off);
    const int rt = row >> 4, rr = row & 15;
    if (c4i >= 50 && c4i < 58) {          // channels 200..231
      const int jj = (c4i - 50) * 4;
      ov.x += olds[rt * 561 + (jj + 0) * 17 + rr];
      ov.y += olds[rt * 561 + (jj + 1) * 17 + rr];
      ov.z += olds[rt * 561 + (jj + 2) * 17 + rr];
      ov.w += olds[rt * 561 + (jj + 3) * 17 + rr];
    } else if (c4i == 66) {               // channel 265 is .y of float4 66
      ov.y += olds[rt * 561 + 32 * 17 + rr];
    }
    *(float4*)(out + off) = ov;
  }
}

extern "C" void kernel_launch(void* const* d_in, const int* in_sizes, int n_in,
                              void* d_out, int out_size, void* d_ws, size_t ws_size,
                              hipStream_t stream) {
  const float* tgt = (const float*)d_in[0];
  const float* mem = (const float*)d_in[1];
  ushort* ws = (ushort*)d_ws;             // needs 3 MB
  float* out = (float*)d_out;
  preproc<<<dim3(256), dim3(256), 0, stream>>>(mem, ws);
  attn_main<<<dim3(512), dim3(BLK), 0, stream>>>(tgt, ws, out);
}

// Round 7
// 29.906 us; speedup vs baseline: 1.3544x; 1.2348x over previous
//
#include <hip/hip_runtime.h>
#include <hip/hip_bf16.h>

// GetInitialSymbol: structured single-head cross-attention + residual.
//   q_i = 2*tgt[136+i]-1 (i<32); k_i = 2*mem[72+i]-1; v_{200+j} = mem[8+j]; v_265 = 1
//   fixed token: score=31, value=0.
// preproc: K' -> fp16, V -> bf16, both in exact per-lane MFMA fragment order in ws.
// attn_main: flash attention with REGISTER-staged fragments (no LDS in hot loop),
// grid 1024 (16 rows/block), 4 waves x 512-key segments, merge at end.
#define B_   8
#define T_   2048
#define S_   2048
#define DIN  512
#define QOFF 136
#define KOFF 72
#define VSRC 8

typedef __attribute__((ext_vector_type(8))) short    bf16x8;
typedef __attribute__((ext_vector_type(8))) _Float16 f16x8;
typedef __attribute__((ext_vector_type(4))) float    f32x4;

constexpr int KSEC = 0;              // ushort offsets in ws (total 2 MB)
constexpr int VSEC = 524288;         // 8 batches x 65536
constexpr int BATCH_U = 65536;

constexpr int BLK = 256;             // 4 waves = 4 key segments of 512
constexpr int NGW = 16;              // 32-key groups per segment

__device__ __forceinline__ ushort f2b(float x) {
  __hip_bfloat16 h = __float2bfloat16(x);
  return __builtin_bit_cast(ushort, h);
}
__device__ __forceinline__ ushort f2h(float x) {
  return __builtin_bit_cast(ushort, (_Float16)x);
}

// ---------- kernel 1: K/V -> fragment-ordered fp16/bf16 in ws ----------
// K'[key][e] -> idx (key>>4)*512 + ((key&15)+16*(e>>3))*8 + (e&7)      [fp16]
// V[key][ch] -> idx (key>>5)*1024 + (ch>>4)*512 + ((ch&15)+16*((key>>2)&3))*8
//               + ((key>>4)&1)*4 + (key&3)                              [bf16]
__global__ __launch_bounds__(256)
void preproc(const float* __restrict__ mem, ushort* __restrict__ ws) {
  const int t   = threadIdx.x;
  const int b   = blockIdx.x >> 5;
  const int key = (blockIdx.x & 31) * 64 + (t >> 2);
  const int cs  = (t & 3) * 8;
  const float* row = mem + ((size_t)b * S_ + key) * DIN;
  const float4 ka = *(const float4*)(row + KOFF + cs);
  const float4 kb = *(const float4*)(row + KOFF + cs + 4);
  const float4 va = *(const float4*)(row + VSRC + cs);
  const float4 vb = *(const float4*)(row + VSRC + cs + 4);
  const float kf[8] = {ka.x, ka.y, ka.z, ka.w, kb.x, kb.y, kb.z, kb.w};
  const float vv[8] = {va.x, va.y, va.z, va.w, vb.x, vb.y, vb.z, vb.w};
  ushort kh[8];
  #pragma unroll
  for (int e = 0; e < 8; ++e) kh[e] = f2h(2.f * kf[e] - 1.f);
  const size_t kidx = (size_t)b * BATCH_U + (key >> 4) * 512
                    + ((key & 15) + 16 * (t & 3)) * 8;   // 8 contiguous slots
  *(uint4*)(ws + KSEC + kidx) = *(const uint4*)kh;
  const int Qk = (key >> 2) & 3;
  const int jk = ((key >> 4) & 1) * 4 + (key & 3);
  ushort* vdst = ws + VSEC + (size_t)b * BATCH_U + (key >> 5) * 1024 + jk;
  #pragma unroll
  for (int c = 0; c < 8; ++c) {
    const int ch = cs + c;
    vdst[(ch >> 4) * 512 + ((ch & 15) + 16 * Qk) * 8] = f2b(vv[c]);
  }
}

// ---------- merge helpers ----------
__device__ __forceinline__ void mwrite(float* d, int lane, float m, float ls,
                                       const f32x4& o0, const f32x4& o1) {
  d[lane] = m;
  d[64 + lane] = ls;
  #pragma unroll
  for (int i = 0; i < 4; ++i) {
    d[128 + i * 64 + lane] = o0[i];
    d[384 + i * 64 + lane] = o1[i];
  }
}
__device__ __forceinline__ void mread(const float* s, int lane, float& m,
                                      float& ls, f32x4& o0, f32x4& o1) {
  const float m1 = s[lane], l1 = s[64 + lane];
  const float mn = fmaxf(m, m1);
  const float sa = __expf(m - mn), sb = __expf(m1 - mn);
  ls = ls * sa + l1 * sb;
  #pragma unroll
  for (int i = 0; i < 4; ++i) {
    o0[i] = o0[i] * sa + s[128 + i * 64 + lane] * sb;
    o1[i] = o1[i] * sa + s[384 + i * 64 + lane] * sb;
  }
  m = mn;
}

// ---------- kernel 2: flash attention, register-staged ----------
__global__ __launch_bounds__(BLK, 4)
void attn_main(const float* __restrict__ tgt, const ushort* __restrict__ ws,
               float* __restrict__ out) {
  __shared__ float msl[3 * 640 + 561];   // 3 merge slots + results (~10 KB)

  const int tid  = threadIdx.x;
  const int lane = tid & 63;
  const int wv   = tid >> 6;             // key segment 0..3
  const int Q    = lane >> 4;
  const int r15  = lane & 15;

  // XCD swizzle: batch == XCD (ws fragments, 256 KB/batch, stay L2-hot)
  const int o  = (blockIdx.x & 7) * 128 + (blockIdx.x >> 3);
  const int b  = o >> 7;
  const int t0 = (o & 127) * 16;

  const ushort* wsK = ws + KSEC + (size_t)b * BATCH_U;
  const ushort* wsV = ws + VSEC + (size_t)b * BATCH_U;

  // P fragment (fp16): element j of lane = p[qrow=r15][8Q+j]
  const float* tr = tgt + ((size_t)(b * T_) + t0 + r15) * DIN + QOFF + 8 * Q;
  const float4 qa = *(const float4*)tr;
  const float4 qb = *(const float4*)(tr + 4);
  f16x8 pf;
  {
    const float pv[8] = {qa.x, qa.y, qa.z, qa.w, qb.x, qb.y, qb.z, qb.w};
    #pragma unroll
    for (int e = 0; e < 8; ++e) pf[e] = (_Float16)(2.f * pv[e] - 1.f);
  }

  float m  = 31.f;                              // fixed token score (exact)
  float ls = (Q == 0 && wv == 0) ? 1.f : 0.f;   // its exp, seeded once per row
  f32x4 oc0 = {0.f, 0.f, 0.f, 0.f}, oc1 = {0.f, 0.f, 0.f, 0.f};

  // Register staging, 2 groups in flight; all indices compile-time static.
  bf16x8 stg[2][4];
  #define ISSUE(g, pb)                                                         \
    { const int ki = (wv * 32 + 2 * (g)) * 512 + lane * 8;                     \
      stg[pb][0] = *(const bf16x8*)(wsK + ki);                                 \
      stg[pb][1] = *(const bf16x8*)(wsK + ki + 512);                           \
      const int vi = (wv * NGW + (g)) * 1024 + lane * 8;                       \
      stg[pb][2] = *(const bf16x8*)(wsV + vi);                                 \
      stg[pb][3] = *(const bf16x8*)(wsV + vi + 512); }

  ISSUE(0, 0)
  ISSUE(1, 1)

  #pragma unroll
  for (int g = 0; g < NGW; ++g) {
    const int pb = g & 1;
    const f16x8  k0 = __builtin_bit_cast(f16x8, stg[pb][0]);
    const f16x8  k1 = __builtin_bit_cast(f16x8, stg[pb][1]);
    const bf16x8 v0 = stg[pb][2];
    const bf16x8 v1 = stg[pb][3];

    // scores: C elem r of lane = score[key = 32g + 16*mt + 4Q + r][qrow = r15]
    f32x4 c0 = {0.f, 0.f, 0.f, 0.f}, c1 = {0.f, 0.f, 0.f, 0.f};
    c0 = __builtin_amdgcn_mfma_f32_16x16x32_f16(k0, pf, c0, 0, 0, 0);
    c1 = __builtin_amdgcn_mfma_f32_16x16x32_f16(k1, pf, c1, 0, 0, 0);

    if (g + 2 < NGW) ISSUE(g + 2, pb)   // prefetch while softmax+PV run

    // online softmax, row-uniform max (shfl over Q groups), defer-threshold 8
    float gm = fmaxf(fmaxf(fmaxf(c0[0], c0[1]), fmaxf(c0[2], c0[3])),
                     fmaxf(fmaxf(c1[0], c1[1]), fmaxf(c1[2], c1[3])));
    gm = fmaxf(gm, __shfl_xor(gm, 16));
    gm = fmaxf(gm, __shfl_xor(gm, 32));
    if (__any(gm > m + 8.f)) {
      const float mn  = gm;             // gm > m somewhere; per-row monotone max
      const float scl = __expf(m - fmaxf(m, mn));
      const float mx  = fmaxf(m, mn);
      m = mx;
      ls *= scl;
      #pragma unroll
      for (int i = 0; i < 4; ++i) { oc0[i] *= scl; oc1[i] *= scl; }
    }

    // W frag: slot j <-> key (j>>2)*16 + 4Q + (j&3)  (same bijection as V frag)
    bf16x8 wf;
    float wsum = 0.f;
    #pragma unroll
    for (int j = 0; j < 8; ++j) {
      const float w = __expf(((j < 4) ? c0[j & 3] : c1[j & 3]) - m);
      wsum += w;
      wf[j] = (short)f2b(w);
    }
    ls += wsum;

    oc0 = __builtin_amdgcn_mfma_f32_16x16x32_bf16(v0, wf, oc0, 0, 0, 0);
    oc1 = __builtin_amdgcn_mfma_f32_16x16x32_bf16(v1, wf, oc1, 0, 0, 0);
  }
  #undef ISSUE

  // ---- merge 4 segments -> wave 0
  if (wv >= 2) mwrite(msl + (wv - 2) * 640, lane, m, ls, oc0, oc1);
  __syncthreads();
  if (wv < 2) mread(msl + wv * 640, lane, m, ls, oc0, oc1);
  __syncthreads();
  if (wv == 1) mwrite(msl, lane, m, ls, oc0, oc1);
  __syncthreads();
  float* olds = msl + 1920;
  if (wv == 0) {
    mread(msl, lane, m, ls, oc0, oc1);
    float t2 = ls + __shfl_xor(ls, 16);        // sum partials across Q-groups
    const float lt  = t2 + __shfl_xor(t2, 32);
    const float inv = 1.f / lt;
    #pragma unroll
    for (int i = 0; i < 4; ++i) {
      olds[(4 * Q + i) * 17 + r15]      = oc0[i] * inv;   // ch 200..215
      olds[(16 + 4 * Q + i) * 17 + r15] = oc1[i] * inv;   // ch 216..231
    }
    if (Q == 0) olds[32 * 17 + r15] = 1.f - __expf(31.f - m) * inv;
  }
  __syncthreads();

  // ---- epilogue: out = tgt + sparse update (ch 200..231, 265); 16 rows
  const size_t base = (size_t)(b * T_ + t0) * DIN;
  #pragma unroll
  for (int k = 0; k < 8; ++k) {
    const int vid = tid + BLK * k;       // 16 rows x 128 float4
    const int row = vid >> 7;
    const int c4i = vid & 127;
    const size_t off = base + (size_t)row * DIN + c4i * 4;
    float4 ov = *(const float4*)(tgt + off);
    if (c4i >= 50 && c4i < 58) {         // channels 200..231
      const int jj = (c4i - 50) * 4;
      ov.x += olds[(jj + 0) * 17 + row];
      ov.y += olds[(jj + 1) * 17 + row];
      ov.z += olds[(jj + 2) * 17 + row];
      ov.w += olds[(jj + 3) * 17 + row];
    } else if (c4i == 66) {              // channel 265 is .y of float4 66
      ov.y += olds[32 * 17 + row];
    }
    *(float4*)(out + off) = ov;
  }
}

extern "C" void kernel_launch(void* const* d_in, const int* in_sizes, int n_in,
                              void* d_out, int out_size, void* d_ws, size_t ws_size,
                              hipStream_t stream) {
  const float* tgt = (const float*)d_in[0];
  const float* mem = (const float*)d_in[1];
  ushort* ws = (ushort*)d_ws;            // needs 2 MB
  float* out = (float*)d_out;
  preproc<<<dim3(256), dim3(256), 0, stream>>>(mem, ws);
  attn_main<<<dim3(B_ * (T_ / 16)), dim3(BLK), 0, stream>>>(tgt, ws, out);
}

// Round 10
// 29.220 us; speedup vs baseline: 1.3862x; 1.0235x over previous
//
#include <hip/hip_runtime.h>
#include <hip/hip_bf16.h>

// GetInitialSymbol: structured single-head cross-attention + residual.
//   q_i = 2*tgt[136+i]-1 (i<32); k_i = 2*mem[72+i]-1; v_{200+j} = mem[8+j]; v_265 = 1
//   fixed token: score=31, value=0.
// preproc: K' -> fp16, V -> bf16, in exact per-lane MFMA fragment order in ws.
// attn_main: register-staged flash attention; tgt->out row copy INTERLEAVED into
// the hot loop (plain stores — nt stores raced the cached tail stores sharing
// cache lines and corrupted replays in Round 9).
#define B_   8
#define T_   2048
#define S_   2048
#define DIN  512
#define QOFF 136
#define KOFF 72
#define VSRC 8

typedef __attribute__((ext_vector_type(8))) short    bf16x8;
typedef __attribute__((ext_vector_type(8))) _Float16 f16x8;
typedef __attribute__((ext_vector_type(4))) float    f32x4;

constexpr int KSEC = 0;              // ushort offsets in ws (total 2 MB)
constexpr int VSEC = 524288;         // 8 batches x 65536
constexpr int BATCH_U = 65536;

constexpr int BLK = 256;             // 4 waves = 4 key segments of 512
constexpr int NGW = 16;              // 32-key groups per segment

__device__ __forceinline__ ushort f2b(float x) {
  __hip_bfloat16 h = __float2bfloat16(x);
  return __builtin_bit_cast(ushort, h);
}
__device__ __forceinline__ ushort f2h(float x) {
  return __builtin_bit_cast(ushort, (_Float16)x);
}

// ---------- kernel 1: K/V -> fragment-ordered fp16/bf16 in ws ----------
// K'[key][e] -> idx (key>>4)*512 + ((key&15)+16*(e>>3))*8 + (e&7)      [fp16]
// V[key][ch] -> idx (key>>5)*1024 + (ch>>4)*512 + ((ch&15)+16*((key>>2)&3))*8
//               + ((key>>4)&1)*4 + (key&3)                              [bf16]
__global__ __launch_bounds__(256)
void preproc(const float* __restrict__ mem, ushort* __restrict__ ws) {
  const int t    = threadIdx.x;
  const int b    = blockIdx.x >> 5;
  const int key0 = (blockIdx.x & 31) * 64;
  const float*  mbase = mem + (size_t)b * S_ * DIN;
  ushort* wk = ws + KSEC + (size_t)b * BATCH_U;
  ushort* wv = ws + VSEC + (size_t)b * BATCH_U;

  // K: 2 reps x 256 lanes cover 64 keys x 8 float4-cols; 8B vector stores.
  #pragma unroll
  for (int rep = 0; rep < 2; ++rep) {
    const int cid = t + 256 * rep;
    const int key = cid >> 3, c = cid & 7;
    const float4 k4 = *(const float4*)(mbase + (size_t)(key0 + key) * DIN + KOFF + 4 * c);
    const float kf[4] = {k4.x, k4.y, k4.z, k4.w};
    ushort kh[4];
    #pragma unroll
    for (int e = 0; e < 4; ++e) kh[e] = f2h(2.f * kf[e] - 1.f);
    const int gkey = key0 + key;
    const int pos  = (gkey >> 4) * 512 + ((gkey & 15) + 16 * (c >> 1)) * 8 + 4 * (c & 1);
    *(uint2*)(wk + pos) = *(const uint2*)kh;
  }

  // V: lane = channel (t&31) x key-octet (t>>5); coalesced loads, 2x8B stores.
  const int ch = t & 31, h = t >> 5;
  float vv[8];
  #pragma unroll
  for (int r = 0; r < 8; ++r)
    vv[r] = mbase[(size_t)(key0 + 8 * h + r) * DIN + VSRC + ch];
  ushort vb[8];
  #pragma unroll
  for (int r = 0; r < 8; ++r) vb[r] = f2b(vv[r]);
  #pragma unroll
  for (int half = 0; half < 2; ++half) {
    const int key = key0 + 8 * h + 4 * half;      // quad base (key&3 == 0)
    const int pos = (key >> 5) * 1024 + (ch >> 4) * 512
                  + ((ch & 15) + 16 * ((key >> 2) & 3)) * 8 + ((key >> 4) & 1) * 4;
    *(uint2*)(wv + pos) = *(const uint2*)&vb[half * 4];
  }
}

// ---------- merge helpers ----------
__device__ __forceinline__ void mwrite(float* d, int lane, float m, float ls,
                                       const f32x4& o0, const f32x4& o1) {
  d[lane] = m;
  d[64 + lane] = ls;
  #pragma unroll
  for (int i = 0; i < 4; ++i) {
    d[128 + i * 64 + lane] = o0[i];
    d[384 + i * 64 + lane] = o1[i];
  }
}
__device__ __forceinline__ void mread(const float* s, int lane, float& m,
                                      float& ls, f32x4& o0, f32x4& o1) {
  const float m1 = s[lane], l1 = s[64 + lane];
  const float mn = fmaxf(m, m1);
  const float sa = __expf(m - mn), sb = __expf(m1 - mn);
  ls = ls * sa + l1 * sb;
  #pragma unroll
  for (int i = 0; i < 4; ++i) {
    o0[i] = o0[i] * sa + s[128 + i * 64 + lane] * sb;
    o1[i] = o1[i] * sa + s[384 + i * 64 + lane] * sb;
  }
  m = mn;
}

// ---------- kernel 2: flash attention + interleaved residual copy ----------
__global__ __launch_bounds__(BLK, 4)
void attn_main(const float* __restrict__ tgt, const ushort* __restrict__ ws,
               float* __restrict__ out) {
  __shared__ float msl[3 * 640 + 561];   // 3 merge slots + results (~10 KB)

  const int tid  = threadIdx.x;
  const int lane = tid & 63;
  const int wv   = tid >> 6;             // key segment 0..3
  const int Q    = lane >> 4;
  const int r15  = lane & 15;

  // XCD swizzle: batch == XCD (ws fragments, 256 KB/batch, stay L2-hot)
  const int o  = (blockIdx.x & 7) * 128 + (blockIdx.x >> 3);
  const int b  = o >> 7;
  const int t0 = (o & 127) * 16;

  const ushort* wsK = ws + KSEC + (size_t)b * BATCH_U;
  const ushort* wsV = ws + VSEC + (size_t)b * BATCH_U;
  const size_t  base = (size_t)(b * T_ + t0) * DIN;

  // P fragment (fp16): element j of lane = p[qrow=r15][8Q+j]
  const float* tr = tgt + base + (size_t)r15 * DIN + QOFF + 8 * Q;
  const float4 qa = *(const float4*)tr;
  const float4 qb = *(const float4*)(tr + 4);
  f16x8 pf;
  {
    const float pv[8] = {qa.x, qa.y, qa.z, qa.w, qb.x, qb.y, qb.z, qb.w};
    #pragma unroll
    for (int e = 0; e < 8; ++e) pf[e] = (_Float16)(2.f * pv[e] - 1.f);
  }

  float m  = 31.f;                              // fixed token score (exact)
  float ls = (Q == 0 && wv == 0) ? 1.f : 0.f;   // its exp, seeded once per row
  f32x4 oc0 = {0.f, 0.f, 0.f, 0.f}, oc1 = {0.f, 0.f, 0.f, 0.f};

  // K/V register staging, 2 groups in flight; indices compile-time static.
  bf16x8 stg[2][4];
  #define ISSUE(g, pb)                                                         \
    { const int ki = (wv * 32 + 2 * (g)) * 512 + lane * 8;                     \
      stg[pb][0] = *(const bf16x8*)(wsK + ki);                                 \
      stg[pb][1] = *(const bf16x8*)(wsK + ki + 512);                           \
      const int vi = (wv * NGW + (g)) * 1024 + lane * 8;                       \
      stg[pb][2] = *(const bf16x8*)(wsV + vi);                                 \
      stg[pb][3] = *(const bf16x8*)(wsV + vi + 512); }

  // Interleaved residual copy: 16 rows x 128 float4 = 2048 = 8 chunks of 256.
  f32x4 cp[2];
  int cpr[2], cpc[2];                    // row / c4-index of in-flight chunks
  #define CLOAD(c, pb)                                                         \
    { const int vid = (c) * BLK + tid;                                         \
      cpr[pb] = vid >> 7; cpc[pb] = vid & 127;                                 \
      cp[pb] = *(const f32x4*)(tgt + base + (size_t)cpr[pb] * DIN + cpc[pb] * 4); }
  #define CSTORE(pb)                                                           \
    { const int cc = cpc[pb];                                                  \
      if (!((cc >= 50 && cc < 58) || cc == 66))                                \
        *(f32x4*)(out + base + (size_t)cpr[pb] * DIN + cc * 4) = cp[pb]; }

  ISSUE(0, 0)
  ISSUE(1, 1)
  CLOAD(0, 0)

  #pragma unroll
  for (int g = 0; g < NGW; ++g) {
    const int pb = g & 1;
    // interleaved copy pipeline: store chunk g-1, load chunk g (chunks 0..7)
    if (g >= 1 && g <= 8) CSTORE((g - 1) & 1)
    if (g >= 1 && g < 8)  CLOAD(g, g & 1)

    const f16x8  k0 = __builtin_bit_cast(f16x8, stg[pb][0]);
    const f16x8  k1 = __builtin_bit_cast(f16x8, stg[pb][1]);
    const bf16x8 v0 = stg[pb][2];
    const bf16x8 v1 = stg[pb][3];

    // scores: C elem r of lane = score[key = 32g + 16*mt + 4Q + r][qrow = r15]
    f32x4 c0 = {0.f, 0.f, 0.f, 0.f}, c1 = {0.f, 0.f, 0.f, 0.f};
    c0 = __builtin_amdgcn_mfma_f32_16x16x32_f16(k0, pf, c0, 0, 0, 0);
    c1 = __builtin_amdgcn_mfma_f32_16x16x32_f16(k1, pf, c1, 0, 0, 0);

    if (g + 2 < NGW) ISSUE(g + 2, pb)   // prefetch while softmax+PV run

    // online softmax, row-uniform max (shfl over Q groups), defer-threshold 8
    float gm = fmaxf(fmaxf(fmaxf(c0[0], c0[1]), fmaxf(c0[2], c0[3])),
                     fmaxf(fmaxf(c1[0], c1[1]), fmaxf(c1[2], c1[3])));
    gm = fmaxf(gm, __shfl_xor(gm, 16));
    gm = fmaxf(gm, __shfl_xor(gm, 32));
    if (__any(gm > m + 8.f)) {
      const float mn  = gm;
      const float scl = __expf(m - fmaxf(m, mn));
      const float mx  = fmaxf(m, mn);
      m = mx;
      ls *= scl;
      #pragma unroll
      for (int i = 0; i < 4; ++i) { oc0[i] *= scl; oc1[i] *= scl; }
    }

    // W frag: slot j <-> key (j>>2)*16 + 4Q + (j&3)  (same bijection as V frag)
    bf16x8 wf;
    float wsum = 0.f;
    #pragma unroll
    for (int j = 0; j < 8; ++j) {
      const float w = __expf(((j < 4) ? c0[j & 3] : c1[j & 3]) - m);
      wsum += w;
      wf[j] = (short)f2b(w);
    }
    ls += wsum;

    oc0 = __builtin_amdgcn_mfma_f32_16x16x32_bf16(v0, wf, oc0, 0, 0, 0);
    oc1 = __builtin_amdgcn_mfma_f32_16x16x32_bf16(v1, wf, oc1, 0, 0, 0);
  }
  #undef ISSUE
  #undef CLOAD
  #undef CSTORE

  // ---- merge 4 segments -> wave 0
  if (wv >= 2) mwrite(msl + (wv - 2) * 640, lane, m, ls, oc0, oc1);
  __syncthreads();
  if (wv < 2) mread(msl + wv * 640, lane, m, ls, oc0, oc1);
  __syncthreads();
  if (wv == 1) mwrite(msl, lane, m, ls, oc0, oc1);
  __syncthreads();
  float* olds = msl + 1920;
  if (wv == 0) {
    mread(msl, lane, m, ls, oc0, oc1);
    float t2 = ls + __shfl_xor(ls, 16);        // sum partials across Q-groups
    const float lt  = t2 + __shfl_xor(t2, 32);
    const float inv = 1.f / lt;
    #pragma unroll
    for (int i = 0; i < 4; ++i) {
      olds[(4 * Q + i) * 17 + r15]      = oc0[i] * inv;   // ch 200..215
      olds[(16 + 4 * Q + i) * 17 + r15] = oc1[i] * inv;   // ch 216..231
    }
    if (Q == 0) olds[32 * 17 + r15] = 1.f - __expf(31.f - m) * inv;
  }
  __syncthreads();

  // ---- attn-touched float4s: 16 rows x 9 (c4 50..57, 66) = 144
  if (tid < 144) {
    const int row = tid / 9, j = tid - row * 9;
    const int c4i = (j < 8) ? (50 + j) : 66;
    const size_t off = base + (size_t)row * DIN + c4i * 4;
    float4 ov = *(const float4*)(tgt + off);
    if (j < 8) {
      ov.x += olds[(4 * j + 0) * 17 + row];
      ov.y += olds[(4 * j + 1) * 17 + row];
      ov.z += olds[(4 * j + 2) * 17 + row];
      ov.w += olds[(4 * j + 3) * 17 + row];
    } else {
      ov.y += olds[32 * 17 + row];             // channel 265
    }
    *(float4*)(out + off) = ov;
  }
}

extern "C" void kernel_launch(void* const* d_in, const int* in_sizes, int n_in,
                              void* d_out, int out_size, void* d_ws, size_t ws_size,
                              hipStream_t stream) {
  const float* tgt = (const float*)d_in[0];
  const float* mem = (const float*)d_in[1];
  ushort* ws = (ushort*)d_ws;            // needs 2 MB
  float* out = (float*)d_out;
  preproc<<<dim3(256), dim3(256), 0, stream>>>(mem, ws);
  attn_main<<<dim3(B_ * (T_ / 16)), dim3(BLK), 0, stream>>>(tgt, ws, out);
}